// Round 10
// baseline (205.121 us; speedup 1.0000x reference)
//
#include <hip/hip_runtime.h>
#include <math.h>

#define CAP  32     // per-node in-edge bucket slots
#define CAPB 4096   // per-bin edge capacity (bins of 256 nodes, E/N*256 = 2048 expected)
#define PART_CHUNK 2048          // smaller chunks -> 2x phase-A blocks (250) -> full-GPU partition
#define PART_ITER (PART_CHUNK/256)

typedef __attribute__((ext_vector_type(8))) short bfrag;   // 8 bf16 (4 VGPRs)
typedef __attribute__((ext_vector_type(4))) float ffrag;   // 4 f32 acc
typedef __attribute__((ext_vector_type(2))) float f2v;     // fp8 pair decode

__device__ __forceinline__ float sigmoidf_(float x){ return 1.f/(1.f+__expf(-x)); }

__device__ __forceinline__ unsigned short f2bf(float f){
    unsigned u = __float_as_uint(f);
    u += 0x7fffu + ((u >> 16) & 1u);      // RNE
    return (unsigned short)(u >> 16);
}
__device__ __forceinline__ float bf2f(unsigned u){
    return __uint_as_float((u & 0xffffu) << 16);
}

// ---------------- prep mega-kernel ----------------
// [0, 2*nA)        : phase-A edge partition, both graphs
// [.., +387)       : combined weights + biases (row-permuted for col-half gemm)
// [.., +B)         : GRU head -> h_out (coalesced tiled-LDS GEMV)
__global__ __launch_bounds__(256) void prep_kernel(
    const int* __restrict__ ei0, const int* __restrict__ ei1,
    int* __restrict__ binCnt, unsigned* __restrict__ bins, int E, int nA, int nb,
    const float* __restrict__ Wlin0, const float* __restrict__ Wattn0,
    const float* __restrict__ blin0, const float* __restrict__ battn0,
    const float* __restrict__ Wlin1, const float* __restrict__ Wattn1,
    const float* __restrict__ blin1, const float* __restrict__ battn1,
    unsigned short* __restrict__ wc, float* __restrict__ bc,
    const float* __restrict__ state_, const float* __restrict__ input_,
    const float* __restrict__ W_in, const float* __restrict__ W_z,
    const float* __restrict__ W_r, const float* __restrict__ W_h,
    float* __restrict__ h_out, int L)
{
    int blk = blockIdx.x;
    if (blk < 2 * nA) {
        // ---- phase A: partition edges into bins of 256 dst nodes ----
        __shared__ int lcnt[128];
        __shared__ int gbase[128];
        int g = (blk >= nA) ? 1 : 0;
        const int* ei = g ? ei1 : ei0;
        int base = (blk - g * nA) * PART_CHUNK;
        int tid = threadIdx.x;
        for (int t = tid; t < nb; t += 256) lcnt[t] = 0;
        __syncthreads();
        int lpos[PART_ITER], binv[PART_ITER]; unsigned wrd[PART_ITER];
        #pragma unroll
        for (int i = 0; i < PART_ITER; ++i) {
            int e = base + i * 256 + tid;
            if (e < E) {
                int d = ei[E + e];
                int s = ei[e];
                int b = d >> 8;
                binv[i] = b;
                wrd[i]  = ((unsigned)(d & 255) << 24) | (unsigned)s;
                lpos[i] = atomicAdd(&lcnt[b], 1);
            } else binv[i] = -1;
        }
        __syncthreads();
        if (tid < nb) gbase[tid] = atomicAdd(&binCnt[g * nb + tid], lcnt[tid]);
        __syncthreads();
        #pragma unroll
        for (int i = 0; i < PART_ITER; ++i) {
            if (binv[i] >= 0) {
                int pos = gbase[binv[i]] + lpos[i];
                if (pos < CAPB) bins[(size_t)(g * nb + binv[i]) * CAPB + pos] = wrd[i];
            }
        }
    } else if (blk < 2 * nA + 387) {
        // ---- combined weights + biases (row-permuted output) ----
        int idx = (blk - 2 * nA) * 256 + threadIdx.x;
        if (idx < 2 * 384 * 128) {
            int layer = idx / 49152;
            int t = idx - layer * 49152;
            int np = t >> 7, k = t & 127;       // np = permuted row
            int g6 = np >> 6, w = np & 63;
            int colHalf = g6 / 3, sec = g6 % 3;
            int n = sec * 128 + colHalf * 64 + w;   // original row
            const float* Wlin  = layer ? Wlin1  : Wlin0;
            const float* Wattn = layer ? Wattn1 : Wattn0;
            float v;
            if (n < 128) {
                v = Wlin[n * 128 + k];
            } else {
                int rr = (n < 256) ? (n - 128) : (n - 256);
                int off = (n < 256) ? 0 : 128;
                float s = 0.f;
                for (int d = 0; d < 128; ++d) s += Wattn[rr * 256 + off + d] * Wlin[d * 128 + k];
                v = s;
            }
            wc[idx] = f2bf(v);
        } else if (idx < 2 * 384 * 128 + 768) {
            // biases stay in ORIGINAL order: [y 0..127 | ai 128..255 | aj 256..383]
            int bi = idx - 2 * 384 * 128;
            int layer = bi / 384;
            int n = bi - layer * 384;
            const float* blin  = layer ? blin1  : blin0;
            const float* Wattn = layer ? Wattn1 : Wattn0;
            const float* battn = layer ? battn1 : battn0;
            float v;
            if (n < 128) v = blin[n];
            else {
                int rr = (n < 256) ? (n - 128) : (n - 256);
                int off = (n < 256) ? 0 : 128;
                float s = 0.f;
                for (int d = 0; d < 128; ++d) s += Wattn[rr * 256 + off + d] * blin[d];
                v = (n < 256) ? (s + battn[rr]) : s;
            }
            bc[bi] = v;
        }
    } else {
        // ---- GRU: coalesced tiled-LDS GEMV ----
        __shared__ float wt[128 * 65];    // one 128x64 f32 tile, pad 65 (conflict-free)
        __shared__ float mu[128], ziv[256], zi2[256], zzv[128], stv[128];
        int tid = threadIdx.x;
        int b = blk - (2 * nA + 387);

        if (tid < 128) {
            float s = 0.f;
            const float* ip = input_ + (size_t)b * L * 128 + tid;
            #pragma unroll 5
            for (int l = 0; l < L; ++l) s += ip[(size_t)l * 128];   // coalesced across tid
            mu[tid] = s / (float)L;
            float st = state_[b * 128 + tid];
            stv[tid] = st;
            ziv[tid] = st;
        }
        __syncthreads();

        #define LOADTILE(W, ldk, k0) { \
            _Pragma("unroll") \
            for (int j = 0; j < 8; ++j) { \
                int f = tid + 256 * j; \
                int row = f >> 4, c4 = (f & 15) << 2; \
                float4 v = *(const float4*)((W) + (size_t)row * (ldk) + (k0) + c4); \
                float* wp = &wt[row * 65 + c4]; \
                wp[0] = v.x; wp[1] = v.y; wp[2] = v.z; wp[3] = v.w; \
            } }
        #define GEMVT(vec, k0, acc) { \
            if (tid < 128) { \
                const float* wr_ = &wt[tid * 65]; \
                _Pragma("unroll") \
                for (int c = 0; c < 64; ++c) acc += wr_[c] * (vec)[(k0) + c]; \
            } }

        float accI = 0.f;
        LOADTILE(W_in, 128, 0);  __syncthreads(); GEMVT(mu, 0, accI);  __syncthreads();
        LOADTILE(W_in, 128, 64); __syncthreads(); GEMVT(mu, 64, accI); __syncthreads();
        if (tid < 128) ziv[128 + tid] = accI;
        __syncthreads();

        float accZ = 0.f;
        #pragma unroll
        for (int t4 = 0; t4 < 4; ++t4) {
            LOADTILE(W_z, 256, t4 * 64); __syncthreads();
            GEMVT(ziv, t4 * 64, accZ);   __syncthreads();
        }
        float accR = 0.f;
        #pragma unroll
        for (int t4 = 0; t4 < 4; ++t4) {
            LOADTILE(W_r, 256, t4 * 64); __syncthreads();
            GEMVT(ziv, t4 * 64, accR);   __syncthreads();
        }
        if (tid < 128) {
            float z = sigmoidf_(accZ), r = sigmoidf_(accR);
            zzv[tid] = z;
            zi2[tid] = r * stv[tid];
            zi2[128 + tid] = ziv[128 + tid];
        }
        __syncthreads();
        float accH = 0.f;
        #pragma unroll
        for (int t4 = 0; t4 < 4; ++t4) {
            LOADTILE(W_h, 256, t4 * 64); __syncthreads();
            GEMVT(zi2, t4 * 64, accH);   __syncthreads();
        }
        if (tid < 128) {
            float hc = tanhf(accH);
            float z = zzv[tid], st = stv[tid];
            h_out[b * 128 + tid] = (1.f - z) * st + z * hc;
        }
        #undef LOADTILE
        #undef GEMVT
    }
}

// ---------------- fused MFMA GEMM, col-half blocks: block = 64 rows x 192 cols
// (one complete {y,ai,aj} triple-set of 64 output cols via the Wc row permutation).
// Grid = 2*(N/64). Wc kk-slice staged in LDS (192 x 32 bf16, rows padded to 40 shorts).
// Trailing blocks (gemm0 only): phase-B CSR build. LDS unioned across roles.
__global__ __launch_bounds__(256) void gemm384(const short* __restrict__ Xb, const float* __restrict__ Xf,
                                               const short* __restrict__ Wc, const float* __restrict__ bc,
                                               unsigned short* __restrict__ aib, unsigned short* __restrict__ pair,
                                               const unsigned* __restrict__ bins, const int* __restrict__ binCnt,
                                               int* __restrict__ cnt, unsigned short* __restrict__ esrc,
                                               int N, int nb, int gemmBlks2)
{
    __shared__ __align__(16) char smem[17408];   // max(192*40*2=15360, 1024+16384)
    if ((int)blockIdx.x >= gemmBlks2) {
        // ---- phase B: build per-node buckets for one bin (256 nodes) in LDS ----
        int* cl = (int*)smem;                                   // 1024 B
        unsigned short* el = (unsigned short*)(smem + 1024);    // 16384 B
        int p = blockIdx.x - gemmBlks2;          // 0 .. 2*nb-1
        int g = (p >= nb) ? 1 : 0;
        int bin = p - g * nb;
        int tid = threadIdx.x;
        cl[tid] = 0;
        __syncthreads();
        int m = binCnt[g * nb + bin]; if (m > CAPB) m = CAPB;
        const unsigned* bp_ = bins + (size_t)(g * nb + bin) * CAPB;
        for (int i = tid; i < m; i += 256) {
            unsigned w = bp_[i];
            int dl = (int)(w >> 24);
            int pp = atomicAdd(&cl[dl], 1);
            if (pp < CAP) el[dl * CAP + pp] = (unsigned short)w;   // src < 32768 fits 16b
        }
        __syncthreads();
        int nodeBase = bin * 256;
        int* cg = cnt + (size_t)g * N;
        if (nodeBase + tid < N) cg[nodeBase + tid] = cl[tid];
        uint4* eo = (uint4*)(esrc + ((size_t)g * N + nodeBase) * CAP);
        const uint4* es = (const uint4*)el;
        #pragma unroll
        for (int k = 0; k < 4; ++k) eo[k * 256 + tid] = es[k * 256 + tid];  // 16 KB coalesced
        return;
    }
    short* wlds = (short*)smem;   // 192 rows x (32 + 8 pad) shorts
    int mtile = blockIdx.x >> 1, colHalf = blockIdx.x & 1;   // adjacent blocks share A rows
    int tid = threadIdx.x;
    int lane = tid & 63, wave = tid >> 6;
    int quad = lane >> 4, l16 = lane & 15;
    int mrow = mtile * 64 + wave * 16 + l16;

    // hoist A fragments for all 4 kk steps
    bfrag av[4];
    if (Xf) {
        #pragma unroll
        for (int kk = 0; kk < 4; ++kk) {
            const float* xfp = Xf + (size_t)mrow * 128 + quad * 8 + kk * 32;
            float4 a0 = *(const float4*)(xfp);
            float4 a1 = *(const float4*)(xfp + 4);
            av[kk] = (bfrag){ (short)f2bf(a0.x), (short)f2bf(a0.y), (short)f2bf(a0.z), (short)f2bf(a0.w),
                              (short)f2bf(a1.x), (short)f2bf(a1.y), (short)f2bf(a1.z), (short)f2bf(a1.w) };
        }
    } else {
        #pragma unroll
        for (int kk = 0; kk < 4; ++kk)
            av[kk] = *(const bfrag*)(Xb + (size_t)mrow * 128 + quad * 8 + kk * 32);
    }

    ffrag acc[12];
    #pragma unroll
    for (int t = 0; t < 12; ++t) acc[t] = (ffrag){0.f, 0.f, 0.f, 0.f};

    const short* Wh = Wc + (size_t)colHalf * 192 * 128;
    #pragma unroll
    for (int kk = 0; kk < 4; ++kk) {
        __syncthreads();          // previous slice's reads complete
        // stage Wc rows [colHalf*192, +192), cols kk*32..+32: 768 16-B chunks / 256 thr
        #pragma unroll
        for (int it = 0; it < 3; ++it) {
            int slot = it * 256 + tid;
            int row = slot >> 2, ch = slot & 3;
            *(bfrag*)&wlds[row * 40 + ch * 8] = *(const bfrag*)(Wh + (size_t)row * 128 + kk * 32 + ch * 8);
        }
        __syncthreads();
        #pragma unroll
        for (int t = 0; t < 12; ++t) {
            bfrag bv = *(const bfrag*)&wlds[(t * 16 + l16) * 40 + quad * 8];
            acc[t] = __builtin_amdgcn_mfma_f32_16x16x32_bf16(av[kk], bv, acc[t], 0, 0, 0);
        }
    }
    // epilogue: tiles 0..3 = y, 4..7 = ai, 8..11 = aj, cols colHalf*64 + tt*16 + l16
    int rbase = mtile * 64 + wave * 16 + quad * 4;
    #pragma unroll
    for (int tt = 0; tt < 4; ++tt) {
        int c = colHalf * 64 + tt * 16 + l16;
        float by = bc[c], bi = bc[128 + c], bj = bc[256 + c];
        #pragma unroll
        for (int r = 0; r < 4; ++r) {
            size_t off = (size_t)(rbase + r) * 128 + c;
            float yv  = acc[tt][r]     + by;
            float aiv = acc[4 + tt][r] + bi;
            float ajv = acc[8 + tt][r] + bj;
            aib[off] = f2bf(aiv);
            int w = __builtin_amdgcn_cvt_pk_fp8_f32(yv, ajv, 0, false);  // byte0=y, byte1=aj
            pair[off] = (unsigned short)w;
        }
    }
}

// ---------------- GAT aggregate: one wave per node; paired-row gather (2 rows per
// load via lane halves). Source indices come from direct broadcast reads of the
// esrc row (all 32 lanes same address -> 1 transaction) instead of shfl chains.
__global__ void aggregate_kernel(const unsigned short* __restrict__ aib, const unsigned* __restrict__ pair,
                                 const int* __restrict__ cnt, const unsigned short* __restrict__ esrc,
                                 unsigned* __restrict__ gb_out,
                                 const float* __restrict__ h, const float* __restrict__ Wp, const float* __restrict__ bp,
                                 const float* __restrict__ Ws, const float* __restrict__ bs,
                                 float* __restrict__ pbuf, float* __restrict__ sisr_out,
                                 int N, int NN, int fuse_score)
{
    int node = blockIdx.x * (blockDim.x >> 6) + (threadIdx.x >> 6);
    if (node >= N) return;
    int lane = threadIdx.x & 63;
    int half = lane >> 5, l32 = lane & 31;
    int c0 = l32 << 2;                       // this lane's 4 columns

    uint2 ainv = *(const uint2*)(aib + ((size_t)node << 7) + c0);
    float a0 = bf2f(ainv.x), a1 = bf2f(ainv.x >> 16);
    float a2 = bf2f(ainv.y), a3 = bf2f(ainv.y >> 16);

    int deg = cnt[node]; if (deg > CAP) deg = CAP;
    int total = deg + 1;                     // + self
    const unsigned short* ep = esrc + (size_t)node * CAP;

    float w0=0.f,w1=0.f,w2=0.f,w3=0.f, o0=0.f,o1=0.f,o2=0.f,o3=0.f;
    const uint2* pr = (const uint2*)pair;    // row = 32 uint2

    #define PROC4(q) { \
        f2v p0 = __builtin_amdgcn_cvt_pk_f32_fp8((int)((q).x), false); \
        f2v p1 = __builtin_amdgcn_cvt_pk_f32_fp8((int)((q).x), true);  \
        f2v p2 = __builtin_amdgcn_cvt_pk_f32_fp8((int)((q).y), false); \
        f2v p3 = __builtin_amdgcn_cvt_pk_f32_fp8((int)((q).y), true);  \
        float t0 = a0 + p0.y, t1 = a1 + p1.y, t2 = a2 + p2.y, t3 = a3 + p3.y; \
        t0 = (t0 > 0.f) ? t0 : 0.2f * t0; t1 = (t1 > 0.f) ? t1 : 0.2f * t1; \
        t2 = (t2 > 0.f) ? t2 : 0.2f * t2; t3 = (t3 > 0.f) ? t3 : 0.2f * t3; \
        float e0 = __expf(t0), e1 = __expf(t1), e2 = __expf(t2), e3 = __expf(t3); \
        w0 += e0; w1 += e1; w2 += e2; w3 += e3; \
        o0 += e0 * p0.x; o1 += e1 * p1.x; o2 += e2 * p2.x; o3 += e3 * p3.x; }

    uint2 q0,q1,q2,q3,q4,q5,q6,q7;
    // issue phase: rows k = 2*i + half, k < total (predicates are half-uniform);
    // k==0 -> self row; else source = broadcast load ep[k-1]
    {
        int k, s;
        #define ISSUE(i, qv) \
            k = 2*(i) + half; \
            if (k < total) { \
                s = (k == 0) ? node : (int)ep[k - 1]; \
                qv = pr[((size_t)s << 5) + l32]; \
            }
        ISSUE(0, q0) ISSUE(1, q1) ISSUE(2, q2) ISSUE(3, q3)
        ISSUE(4, q4) ISSUE(5, q5) ISSUE(6, q6) ISSUE(7, q7)
        #undef ISSUE
    }
    // process phase (same half-uniform predicates)
    if (0 + half < total) PROC4(q0)
    if (2 + half < total) PROC4(q1)
    if (4 + half < total) PROC4(q2)
    if (6 + half < total) PROC4(q3)
    if (8 + half < total) PROC4(q4)
    if (10 + half < total) PROC4(q5)
    if (12 + half < total) PROC4(q6)
    if (14 + half < total) PROC4(q7)
    // rare overflow (deg > 15)
    for (int k = 16 + half; k < total; k += 2) {
        int s = (int)ep[k - 1];
        uint2 q = pr[((size_t)s << 5) + l32];
        PROC4(q)
    }
    #undef PROC4

    // merge lo/hi partial sums (both halves end with full sums)
    w0 += __shfl_xor(w0, 32); w1 += __shfl_xor(w1, 32);
    w2 += __shfl_xor(w2, 32); w3 += __shfl_xor(w3, 32);
    o0 += __shfl_xor(o0, 32); o1 += __shfl_xor(o1, 32);
    o2 += __shfl_xor(o2, 32); o3 += __shfl_xor(o3, 32);

    float g0 = o0 / (w0 + 1e-16f), g1 = o1 / (w1 + 1e-16f);
    float g2 = o2 / (w2 + 1e-16f), g3 = o3 / (w3 + 1e-16f);

    if (!fuse_score) {
        if (half == 0) {
            uint2 outv;
            outv.x = (unsigned)f2bf(g0) | ((unsigned)f2bf(g1) << 16);
            outv.y = (unsigned)f2bf(g2) | ((unsigned)f2bf(g3) << 16);
            *(uint2*)(gb_out + (size_t)node * 64 + 2 * l32) = outv;
        }
    } else {
        int b = node / NN;
        float4 hv = *(const float4*)(h + b * 128 + c0);
        float4 wp = *(const float4*)(Wp + c0);
        float4 ws = *(const float4*)(Ws + c0);
        float xg0 = g0 * hv.x, xg1 = g1 * hv.y, xg2 = g2 * hv.z, xg3 = g3 * hv.w;
        float pp = xg0 * wp.x + xg1 * wp.y + xg2 * wp.z + xg3 * wp.w;
        float ss = xg0 * ws.x + xg1 * ws.y + xg2 * ws.z + xg3 * ws.w;
        #pragma unroll
        for (int o = 16; o > 0; o >>= 1) { pp += __shfl_xor(pp, o); ss += __shfl_xor(ss, o); }
        if (lane == 0) {
            pbuf[node] = pp + bp[0];
            sisr_out[node] = sigmoidf_(ss + bs[0]);
        }
    }
}

// softmax over nodes 1..NN-1 per batch row (NN <= 512)
__global__ void softmax_kernel(const float* __restrict__ pbuf, float* __restrict__ prob_out, int NN){
    int b = blockIdx.x, tid = threadIdx.x;
    __shared__ float sdata[512];
    bool valid = (tid >= 1 && tid < NN);
    float v = valid ? pbuf[b * NN + tid] : -INFINITY;
    sdata[tid] = v; __syncthreads();
    for (int o = 256; o > 0; o >>= 1) { if (tid < o) sdata[tid] = fmaxf(sdata[tid], sdata[tid + o]); __syncthreads(); }
    float m = sdata[0]; __syncthreads();
    float e = valid ? __expf(v - m) : 0.f;
    sdata[tid] = e; __syncthreads();
    for (int o = 256; o > 0; o >>= 1) { if (tid < o) sdata[tid] += sdata[tid + o]; __syncthreads(); }
    float ssum = sdata[0];
    if (valid) prob_out[(size_t)b * (NN - 1) + tid - 1] = e / ssum;
}

extern "C" void kernel_launch(void* const* d_in, const int* in_sizes, int n_in,
                              void* d_out, int out_size, void* d_ws, size_t ws_size,
                              hipStream_t stream)
{
    const float* x       = (const float*)d_in[0];
    const int*   ei0     = (const int*)d_in[1];
    const int*   ei1     = (const int*)d_in[2];
    const float* state_  = (const float*)d_in[3];
    const float* input_  = (const float*)d_in[4];
    const float* W_in    = (const float*)d_in[5];
    const float* W_z     = (const float*)d_in[6];
    const float* W_r     = (const float*)d_in[7];
    const float* W_h     = (const float*)d_in[8];
    const float* g0_Wlin = (const float*)d_in[9];
    const float* g0_blin = (const float*)d_in[10];
    const float* g0_Wattn= (const float*)d_in[11];
    const float* g0_battn= (const float*)d_in[12];
    const float* g1_Wlin = (const float*)d_in[13];
    const float* g1_blin = (const float*)d_in[14];
    const float* g1_Wattn= (const float*)d_in[15];
    const float* g1_battn= (const float*)d_in[16];
    const float* Wp      = (const float*)d_in[17];
    const float* bp      = (const float*)d_in[18];
    const float* Ws      = (const float*)d_in[19];
    const float* bs      = (const float*)d_in[20];

    const int N  = in_sizes[0] / 128;       // 32000
    const int E  = in_sizes[1] / 2;         // 256000
    const int B  = in_sizes[3] / 128;       // 64
    const int L  = in_sizes[4] / (B * 128); // 50
    const int NN = N / B;                   // 500
    const int nb = N >> 8;                  // 125 bins of 256 nodes

    float* out      = (float*)d_out;
    float* prob_out = out;                               // B*(NN-1)
    float* sisr_out = out + (size_t)B * (NN - 1);        // B*NN
    float* h_out    = sisr_out + (size_t)B * NN;         // B*128

    // workspace layout (~33.4 MB)
    unsigned short* aib = (unsigned short*)d_ws;         // N*128 bf16 (ai)
    unsigned* gbb  = (unsigned*)(aib + (size_t)N * 128); // N*64 packed bf16x2 (g rows)
    unsigned short* pair = (unsigned short*)(gbb + (size_t)N * 64);  // N*128 ushort {fp8 y, fp8 aj}
    unsigned short* wc = pair + (size_t)N * 128;         // 2*384*128 bf16 (row-permuted)
    float* bc   = (float*)(wc + 2 * 384 * 128);          // 2*384 f32
    float* pbuf = bc + 768;                              // N f32
    int* cnt0  = (int*)(pbuf + N);                       // N (graph0), N (graph1) contiguous
    int* cnt1  = cnt0 + N;
    unsigned short* esrc0 = (unsigned short*)(cnt1 + N); // N*CAP ushort (graph0), then graph1
    unsigned short* esrc1 = esrc0 + (size_t)N * CAP;
    unsigned* bins = (unsigned*)(esrc1 + (size_t)N * CAP); // 2*nb*CAPB packed edges
    int* binCnt = (int*)(bins + (size_t)2 * nb * CAPB);    // 2*nb

    // --- zero bin counters (1 KB; per-node cnt is fully written by phase B) ---
    hipMemsetAsync(binCnt, 0, (size_t)2 * nb * sizeof(int), stream);

    // --- prep: phase-A partition + weight-combine + GRU ---
    const int nA = (E + PART_CHUNK - 1) / PART_CHUNK;    // 125 blocks per graph
    prep_kernel<<<2 * nA + 387 + B, 256, 0, stream>>>(
        ei0, ei1, binCnt, bins, E, nA, nb,
        g0_Wlin, g0_Wattn, g0_blin, g0_battn,
        g1_Wlin, g1_Wattn, g1_blin, g1_battn,
        wc, bc,
        state_, input_, W_in, W_z, W_r, W_h, h_out, L);

    const int gemmBlks2 = 2 * (N / 64);     // 1000 (col-half split)

    // --- layer-0 GEMM + phase-B bucket build for BOTH graphs (trailing 2*nb blocks) ---
    gemm384<<<gemmBlks2 + 2 * nb, 256, 0, stream>>>(nullptr, x, (const short*)wc, bc, aib, pair,
                                                    bins, binCnt, cnt0, esrc0, N, nb, gemmBlks2);

    // --- layer-0 aggregate ---
    aggregate_kernel<<<(N + 3) / 4, 256, 0, stream>>>(aib, (const unsigned*)pair, cnt0, esrc0, gbb,
                                                      nullptr, nullptr, nullptr, nullptr, nullptr,
                                                      nullptr, nullptr, N, NN, 0);

    // --- layer-1 GEMM (bf16 g) ---
    gemm384<<<gemmBlks2, 256, 0, stream>>>((const short*)gbb, nullptr, (const short*)(wc + 49152), bc + 384, aib, pair,
                                           nullptr, nullptr, nullptr, nullptr, N, nb, gemmBlks2);

    // --- layer-1 aggregate + fused readout ---
    aggregate_kernel<<<(N + 3) / 4, 256, 0, stream>>>(aib, (const unsigned*)pair, cnt1, esrc1, nullptr,
                                                      h_out, Wp, bp, Ws, bs,
                                                      pbuf, sisr_out, N, NN, 1);

    // --- softmax ---
    softmax_kernel<<<B, 512, 0, stream>>>(pbuf, prob_out, NN);
}

// Round 11
// 197.533 us; speedup vs baseline: 1.0384x; 1.0384x over previous
//
#include <hip/hip_runtime.h>
#include <math.h>

#define CAP  32     // per-node in-edge bucket slots
#define CAPB 4096   // per-bin edge capacity (bins of 256 nodes, E/N*256 = 2048 expected)
#define PART_CHUNK 4096   // r10 falsified 2048: per-block fixed cost (125 gbase atomics + barriers) eats the gain

typedef __attribute__((ext_vector_type(8))) short bfrag;   // 8 bf16 (4 VGPRs)
typedef __attribute__((ext_vector_type(4))) float ffrag;   // 4 f32 acc
typedef __attribute__((ext_vector_type(2))) float f2v;     // fp8 pair decode

__device__ __forceinline__ float sigmoidf_(float x){ return 1.f/(1.f+__expf(-x)); }

__device__ __forceinline__ unsigned short f2bf(float f){
    unsigned u = __float_as_uint(f);
    u += 0x7fffu + ((u >> 16) & 1u);      // RNE
    return (unsigned short)(u >> 16);
}
__device__ __forceinline__ float bf2f(unsigned u){
    return __uint_as_float((u & 0xffffu) << 16);
}

// ---------------- prep mega-kernel ----------------
// [0, 2*nA)        : phase-A edge partition, both graphs
// [.., +387)       : combined weights + biases.  Wc row order is PERMUTED into
//                    6 groups of 64: [y0-63|ai0-63|aj0-63|y64-127|ai64-127|aj64-127]
//                    so a 192-row half is a complete {y,ai,aj} triple set for 64
//                    output cols -> gemm can split into col-halves (2x grid) while
//                    keeping the fused pair/aib epilogue wave-local.
// [.., +B)         : GRU head -> h_out (coalesced tiled-LDS GEMV)
__global__ __launch_bounds__(256) void prep_kernel(
    const int* __restrict__ ei0, const int* __restrict__ ei1,
    int* __restrict__ binCnt, unsigned* __restrict__ bins, int E, int nA, int nb,
    const float* __restrict__ Wlin0, const float* __restrict__ Wattn0,
    const float* __restrict__ blin0, const float* __restrict__ battn0,
    const float* __restrict__ Wlin1, const float* __restrict__ Wattn1,
    const float* __restrict__ blin1, const float* __restrict__ battn1,
    unsigned short* __restrict__ wc, float* __restrict__ bc,
    const float* __restrict__ state_, const float* __restrict__ input_,
    const float* __restrict__ W_in, const float* __restrict__ W_z,
    const float* __restrict__ W_r, const float* __restrict__ W_h,
    float* __restrict__ h_out, int L)
{
    int blk = blockIdx.x;
    if (blk < 2 * nA) {
        // ---- phase A: partition edges into bins of 256 dst nodes ----
        __shared__ int lcnt[128];
        __shared__ int gbase[128];
        int g = (blk >= nA) ? 1 : 0;
        const int* ei = g ? ei1 : ei0;
        int base = (blk - g * nA) * PART_CHUNK;
        int tid = threadIdx.x;
        for (int t = tid; t < nb; t += 256) lcnt[t] = 0;
        __syncthreads();
        int lpos[16], binv[16]; unsigned wrd[16];
        #pragma unroll
        for (int i = 0; i < 16; ++i) {
            int e = base + i * 256 + tid;
            if (e < E) {
                int d = ei[E + e];
                int s = ei[e];
                int b = d >> 8;
                binv[i] = b;
                wrd[i]  = ((unsigned)(d & 255) << 24) | (unsigned)s;
                lpos[i] = atomicAdd(&lcnt[b], 1);
            } else binv[i] = -1;
        }
        __syncthreads();
        if (tid < nb) gbase[tid] = atomicAdd(&binCnt[g * nb + tid], lcnt[tid]);
        __syncthreads();
        #pragma unroll
        for (int i = 0; i < 16; ++i) {
            if (binv[i] >= 0) {
                int pos = gbase[binv[i]] + lpos[i];
                if (pos < CAPB) bins[(size_t)(g * nb + binv[i]) * CAPB + pos] = wrd[i];
            }
        }
    } else if (blk < 2 * nA + 387) {
        // ---- combined weights + biases (row-permuted output) ----
        int idx = (blk - 2 * nA) * 256 + threadIdx.x;
        if (idx < 2 * 384 * 128) {
            int layer = idx / 49152;
            int t = idx - layer * 49152;
            int np = t >> 7, k = t & 127;       // np = permuted row
            int g6 = np >> 6, w = np & 63;
            int colHalf = g6 / 3, sec = g6 % 3;
            int n = sec * 128 + colHalf * 64 + w;   // original row
            const float* Wlin  = layer ? Wlin1  : Wlin0;
            const float* Wattn = layer ? Wattn1 : Wattn0;
            float v;
            if (n < 128) {
                v = Wlin[n * 128 + k];
            } else {
                int rr = (n < 256) ? (n - 128) : (n - 256);
                int off = (n < 256) ? 0 : 128;
                float s = 0.f;
                for (int d = 0; d < 128; ++d) s += Wattn[rr * 256 + off + d] * Wlin[d * 128 + k];
                v = s;
            }
            wc[idx] = f2bf(v);
        } else if (idx < 2 * 384 * 128 + 768) {
            // biases stay in ORIGINAL order: [y 0..127 | ai 128..255 | aj 256..383]
            int bi = idx - 2 * 384 * 128;
            int layer = bi / 384;
            int n = bi - layer * 384;
            const float* blin  = layer ? blin1  : blin0;
            const float* Wattn = layer ? Wattn1 : Wattn0;
            const float* battn = layer ? battn1 : battn0;
            float v;
            if (n < 128) v = blin[n];
            else {
                int rr = (n < 256) ? (n - 128) : (n - 256);
                int off = (n < 256) ? 0 : 128;
                float s = 0.f;
                for (int d = 0; d < 128; ++d) s += Wattn[rr * 256 + off + d] * blin[d];
                v = (n < 256) ? (s + battn[rr]) : s;
            }
            bc[bi] = v;
        }
    } else {
        // ---- GRU: coalesced tiled-LDS GEMV ----
        __shared__ float wt[128 * 65];    // one 128x64 f32 tile, pad 65 (conflict-free)
        __shared__ float mu[128], ziv[256], zi2[256], zzv[128], stv[128];
        int tid = threadIdx.x;
        int b = blk - (2 * nA + 387);

        if (tid < 128) {
            float s = 0.f;
            const float* ip = input_ + (size_t)b * L * 128 + tid;
            #pragma unroll 5
            for (int l = 0; l < L; ++l) s += ip[(size_t)l * 128];   // coalesced across tid
            mu[tid] = s / (float)L;
            float st = state_[b * 128 + tid];
            stv[tid] = st;
            ziv[tid] = st;
        }
        __syncthreads();

        #define LOADTILE(W, ldk, k0) { \
            _Pragma("unroll") \
            for (int j = 0; j < 8; ++j) { \
                int f = tid + 256 * j; \
                int row = f >> 4, c4 = (f & 15) << 2; \
                float4 v = *(const float4*)((W) + (size_t)row * (ldk) + (k0) + c4); \
                float* wp = &wt[row * 65 + c4]; \
                wp[0] = v.x; wp[1] = v.y; wp[2] = v.z; wp[3] = v.w; \
            } }
        #define GEMVT(vec, k0, acc) { \
            if (tid < 128) { \
                const float* wr_ = &wt[tid * 65]; \
                _Pragma("unroll") \
                for (int c = 0; c < 64; ++c) acc += wr_[c] * (vec)[(k0) + c]; \
            } }

        float accI = 0.f;
        LOADTILE(W_in, 128, 0);  __syncthreads(); GEMVT(mu, 0, accI);  __syncthreads();
        LOADTILE(W_in, 128, 64); __syncthreads(); GEMVT(mu, 64, accI); __syncthreads();
        if (tid < 128) ziv[128 + tid] = accI;
        __syncthreads();

        float accZ = 0.f;
        #pragma unroll
        for (int t4 = 0; t4 < 4; ++t4) {
            LOADTILE(W_z, 256, t4 * 64); __syncthreads();
            GEMVT(ziv, t4 * 64, accZ);   __syncthreads();
        }
        float accR = 0.f;
        #pragma unroll
        for (int t4 = 0; t4 < 4; ++t4) {
            LOADTILE(W_r, 256, t4 * 64); __syncthreads();
            GEMVT(ziv, t4 * 64, accR);   __syncthreads();
        }
        if (tid < 128) {
            float z = sigmoidf_(accZ), r = sigmoidf_(accR);
            zzv[tid] = z;
            zi2[tid] = r * stv[tid];
            zi2[128 + tid] = ziv[128 + tid];
        }
        __syncthreads();
        float accH = 0.f;
        #pragma unroll
        for (int t4 = 0; t4 < 4; ++t4) {
            LOADTILE(W_h, 256, t4 * 64); __syncthreads();
            GEMVT(zi2, t4 * 64, accH);   __syncthreads();
        }
        if (tid < 128) {
            float hc = tanhf(accH);
            float z = zzv[tid], st = stv[tid];
            h_out[b * 128 + tid] = (1.f - z) * st + z * hc;
        }
        #undef LOADTILE
        #undef GEMVT
    }
}

// ---------------- fused MFMA GEMM, col-half blocks: block = 64 rows x 192 cols
// (one complete {y,ai,aj} triple-set of 64 output cols thanks to the Wc row
// permutation). Grid = 2*(N/64) -> ~4 blocks/CU. 12 acc tiles/wave.
// Wc kk-slice of this half staged in LDS (192 x 32 bf16, rows padded to 40 shorts).
// Trailing blocks (gemm0 only): phase-B CSR build. LDS unioned across roles.
__global__ __launch_bounds__(256) void gemm384(const short* __restrict__ Xb, const float* __restrict__ Xf,
                                               const short* __restrict__ Wc, const float* __restrict__ bc,
                                               unsigned short* __restrict__ aib, unsigned short* __restrict__ pair,
                                               const unsigned* __restrict__ bins, const int* __restrict__ binCnt,
                                               int* __restrict__ cnt, unsigned short* __restrict__ esrc,
                                               int N, int nb, int gemmBlks2)
{
    __shared__ __align__(16) char smem[17408];   // max(192*40*2=15360, 1024+16384)
    if ((int)blockIdx.x >= gemmBlks2) {
        // ---- phase B: build per-node buckets for one bin (256 nodes) in LDS ----
        int* cl = (int*)smem;                                   // 1024 B
        unsigned short* el = (unsigned short*)(smem + 1024);    // 16384 B
        int p = blockIdx.x - gemmBlks2;          // 0 .. 2*nb-1
        int g = (p >= nb) ? 1 : 0;
        int bin = p - g * nb;
        int tid = threadIdx.x;
        cl[tid] = 0;
        __syncthreads();
        int m = binCnt[g * nb + bin]; if (m > CAPB) m = CAPB;
        const unsigned* bp_ = bins + (size_t)(g * nb + bin) * CAPB;
        for (int i = tid; i < m; i += 256) {
            unsigned w = bp_[i];
            int dl = (int)(w >> 24);
            int pp = atomicAdd(&cl[dl], 1);
            if (pp < CAP) el[dl * CAP + pp] = (unsigned short)w;   // src < 32768 fits 16b
        }
        __syncthreads();
        int nodeBase = bin * 256;
        int* cg = cnt + (size_t)g * N;
        if (nodeBase + tid < N) cg[nodeBase + tid] = cl[tid];
        uint4* eo = (uint4*)(esrc + ((size_t)g * N + nodeBase) * CAP);
        const uint4* es = (const uint4*)el;
        #pragma unroll
        for (int k = 0; k < 4; ++k) eo[k * 256 + tid] = es[k * 256 + tid];  // 16 KB coalesced
        return;
    }
    short* wlds = (short*)smem;   // 192 rows x (32 + 8 pad) shorts
    int mtile = blockIdx.x >> 1, colHalf = blockIdx.x & 1;   // adjacent blocks share A rows
    int tid = threadIdx.x;
    int lane = tid & 63, wave = tid >> 6;
    int quad = lane >> 4, l16 = lane & 15;
    int mrow = mtile * 64 + wave * 16 + l16;

    // hoist A fragments for all 4 kk steps
    bfrag av[4];
    if (Xf) {
        #pragma unroll
        for (int kk = 0; kk < 4; ++kk) {
            const float* xfp = Xf + (size_t)mrow * 128 + quad * 8 + kk * 32;
            float4 a0 = *(const float4*)(xfp);
            float4 a1 = *(const float4*)(xfp + 4);
            av[kk] = (bfrag){ (short)f2bf(a0.x), (short)f2bf(a0.y), (short)f2bf(a0.z), (short)f2bf(a0.w),
                              (short)f2bf(a1.x), (short)f2bf(a1.y), (short)f2bf(a1.z), (short)f2bf(a1.w) };
        }
    } else {
        #pragma unroll
        for (int kk = 0; kk < 4; ++kk)
            av[kk] = *(const bfrag*)(Xb + (size_t)mrow * 128 + quad * 8 + kk * 32);
    }

    ffrag acc[12];
    #pragma unroll
    for (int t = 0; t < 12; ++t) acc[t] = (ffrag){0.f, 0.f, 0.f, 0.f};

    const short* Wh = Wc + (size_t)colHalf * 192 * 128;
    #pragma unroll
    for (int kk = 0; kk < 4; ++kk) {
        __syncthreads();          // previous slice's reads complete
        // stage Wc rows [colHalf*192, +192), cols kk*32..+32: 768 16-B chunks / 256 thr
        #pragma unroll
        for (int it = 0; it < 3; ++it) {
            int slot = it * 256 + tid;
            int row = slot >> 2, ch = slot & 3;
            *(bfrag*)&wlds[row * 40 + ch * 8] = *(const bfrag*)(Wh + (size_t)row * 128 + kk * 32 + ch * 8);
        }
        __syncthreads();
        #pragma unroll
        for (int t = 0; t < 12; ++t) {
            bfrag bv = *(const bfrag*)&wlds[(t * 16 + l16) * 40 + quad * 8];
            acc[t] = __builtin_amdgcn_mfma_f32_16x16x32_bf16(av[kk], bv, acc[t], 0, 0, 0);
        }
    }
    // epilogue: tiles 0..3 = y, 4..7 = ai, 8..11 = aj, cols colHalf*64 + tt*16 + l16
    int rbase = mtile * 64 + wave * 16 + quad * 4;
    #pragma unroll
    for (int tt = 0; tt < 4; ++tt) {
        int c = colHalf * 64 + tt * 16 + l16;
        float by = bc[c], bi = bc[128 + c], bj = bc[256 + c];
        #pragma unroll
        for (int r = 0; r < 4; ++r) {
            size_t off = (size_t)(rbase + r) * 128 + c;
            float yv  = acc[tt][r]     + by;
            float aiv = acc[4 + tt][r] + bi;
            float ajv = acc[8 + tt][r] + bj;
            aib[off] = f2bf(aiv);
            int w = __builtin_amdgcn_cvt_pk_fp8_f32(yv, ajv, 0, false);  // byte0=y, byte1=aj
            pair[off] = (unsigned short)w;
        }
    }
}

// ---------------- GAT aggregate: one wave per node; paired-row gather (2 rows
// per load instruction via lane halves); merged with shfl_xor(32).
// r10 falsified broadcast-ep variant (2-deep dependent load chains); load-once+shfl
// keeps every gather a 1-deep chain with 8 in flight.
__global__ void aggregate_kernel(const unsigned short* __restrict__ aib, const unsigned* __restrict__ pair,
                                 const int* __restrict__ cnt, const unsigned short* __restrict__ esrc,
                                 unsigned* __restrict__ gb_out,
                                 const float* __restrict__ h, const float* __restrict__ Wp, const float* __restrict__ bp,
                                 const float* __restrict__ Ws, const float* __restrict__ bs,
                                 float* __restrict__ pbuf, float* __restrict__ sisr_out,
                                 int N, int NN, int fuse_score)
{
    int node = blockIdx.x * (blockDim.x >> 6) + (threadIdx.x >> 6);
    if (node >= N) return;
    int lane = threadIdx.x & 63;
    int half = lane >> 5, l32 = lane & 31;
    int c0 = l32 << 2;                       // this lane's 4 columns

    uint2 ainv = *(const uint2*)(aib + ((size_t)node << 7) + c0);
    float a0 = bf2f(ainv.x), a1 = bf2f(ainv.x >> 16);
    float a2 = bf2f(ainv.y), a3 = bf2f(ainv.y >> 16);

    int deg = cnt[node]; if (deg > CAP) deg = CAP;
    int total = deg + 1;                     // + self
    const unsigned short* ep = esrc + (size_t)node * CAP;
    int myidx = (lane < deg) ? (int)ep[lane] : 0;

    float w0=0.f,w1=0.f,w2=0.f,w3=0.f, o0=0.f,o1=0.f,o2=0.f,o3=0.f;
    const uint2* pr = (const uint2*)pair;    // row = 32 uint2

    #define PROC4(q) { \
        f2v p0 = __builtin_amdgcn_cvt_pk_f32_fp8((int)((q).x), false); \
        f2v p1 = __builtin_amdgcn_cvt_pk_f32_fp8((int)((q).x), true);  \
        f2v p2 = __builtin_amdgcn_cvt_pk_f32_fp8((int)((q).y), false); \
        f2v p3 = __builtin_amdgcn_cvt_pk_f32_fp8((int)((q).y), true);  \
        float t0 = a0 + p0.y, t1 = a1 + p1.y, t2 = a2 + p2.y, t3 = a3 + p3.y; \
        t0 = (t0 > 0.f) ? t0 : 0.2f * t0; t1 = (t1 > 0.f) ? t1 : 0.2f * t1; \
        t2 = (t2 > 0.f) ? t2 : 0.2f * t2; t3 = (t3 > 0.f) ? t3 : 0.2f * t3; \
        float e0 = __expf(t0), e1 = __expf(t1), e2 = __expf(t2), e3 = __expf(t3); \
        w0 += e0; w1 += e1; w2 += e2; w3 += e3; \
        o0 += e0 * p0.x; o1 += e1 * p1.x; o2 += e2 * p2.x; o3 += e3 * p3.x; }

    uint2 q0,q1,q2,q3,q4,q5,q6,q7;
    // issue phase: rows k = 2*i + half, k < total  (conditions are half-uniform)
    {
        int k, kk, sv, s;
        #define ISSUE(i, qv) \
            k = 2*(i) + half; \
            if (k < total) { \
                kk = (k > 0) ? (k - 1) : 0; \
                sv = __shfl(myidx, kk); \
                s  = (k == 0) ? node : sv; \
                qv = pr[((size_t)s << 5) + l32]; \
            }
        ISSUE(0, q0) ISSUE(1, q1) ISSUE(2, q2) ISSUE(3, q3)
        ISSUE(4, q4) ISSUE(5, q5) ISSUE(6, q6) ISSUE(7, q7)
        #undef ISSUE
    }
    // process phase (same half-uniform predicates)
    if (0 + half < total) PROC4(q0)
    if (2 + half < total) PROC4(q1)
    if (4 + half < total) PROC4(q2)
    if (6 + half < total) PROC4(q3)
    if (8 + half < total) PROC4(q4)
    if (10 + half < total) PROC4(q5)
    if (12 + half < total) PROC4(q6)
    if (14 + half < total) PROC4(q7)
    // rare overflow (deg > 15)
    for (int k = 16 + half; k < total; k += 2) {
        int sv = __shfl(myidx, k - 1);
        uint2 q = pr[((size_t)sv << 5) + l32];
        PROC4(q)
    }
    #undef PROC4

    // merge lo/hi partial sums (both halves end with full sums)
    w0 += __shfl_xor(w0, 32); w1 += __shfl_xor(w1, 32);
    w2 += __shfl_xor(w2, 32); w3 += __shfl_xor(w3, 32);
    o0 += __shfl_xor(o0, 32); o1 += __shfl_xor(o1, 32);
    o2 += __shfl_xor(o2, 32); o3 += __shfl_xor(o3, 32);

    float g0 = o0 / (w0 + 1e-16f), g1 = o1 / (w1 + 1e-16f);
    float g2 = o2 / (w2 + 1e-16f), g3 = o3 / (w3 + 1e-16f);

    if (!fuse_score) {
        if (half == 0) {
            uint2 outv;
            outv.x = (unsigned)f2bf(g0) | ((unsigned)f2bf(g1) << 16);
            outv.y = (unsigned)f2bf(g2) | ((unsigned)f2bf(g3) << 16);
            *(uint2*)(gb_out + (size_t)node * 64 + 2 * l32) = outv;
        }
    } else {
        int b = node / NN;
        float4 hv = *(const float4*)(h + b * 128 + c0);
        float4 wp = *(const float4*)(Wp + c0);
        float4 ws = *(const float4*)(Ws + c0);
        float xg0 = g0 * hv.x, xg1 = g1 * hv.y, xg2 = g2 * hv.z, xg3 = g3 * hv.w;
        float pp = xg0 * wp.x + xg1 * wp.y + xg2 * wp.z + xg3 * wp.w;
        float ss = xg0 * ws.x + xg1 * ws.y + xg2 * ws.z + xg3 * ws.w;
        #pragma unroll
        for (int o = 16; o > 0; o >>= 1) { pp += __shfl_xor(pp, o); ss += __shfl_xor(ss, o); }
        if (lane == 0) {
            pbuf[node] = pp + bp[0];
            sisr_out[node] = sigmoidf_(ss + bs[0]);
        }
    }
}

// softmax over nodes 1..NN-1 per batch row (NN <= 512)
__global__ void softmax_kernel(const float* __restrict__ pbuf, float* __restrict__ prob_out, int NN){
    int b = blockIdx.x, tid = threadIdx.x;
    __shared__ float sdata[512];
    bool valid = (tid >= 1 && tid < NN);
    float v = valid ? pbuf[b * NN + tid] : -INFINITY;
    sdata[tid] = v; __syncthreads();
    for (int o = 256; o > 0; o >>= 1) { if (tid < o) sdata[tid] = fmaxf(sdata[tid], sdata[tid + o]); __syncthreads(); }
    float m = sdata[0]; __syncthreads();
    float e = valid ? __expf(v - m) : 0.f;
    sdata[tid] = e; __syncthreads();
    for (int o = 256; o > 0; o >>= 1) { if (tid < o) sdata[tid] += sdata[tid + o]; __syncthreads(); }
    float ssum = sdata[0];
    if (valid) prob_out[(size_t)b * (NN - 1) + tid - 1] = e / ssum;
}

extern "C" void kernel_launch(void* const* d_in, const int* in_sizes, int n_in,
                              void* d_out, int out_size, void* d_ws, size_t ws_size,
                              hipStream_t stream)
{
    const float* x       = (const float*)d_in[0];
    const int*   ei0     = (const int*)d_in[1];
    const int*   ei1     = (const int*)d_in[2];
    const float* state_  = (const float*)d_in[3];
    const float* input_  = (const float*)d_in[4];
    const float* W_in    = (const float*)d_in[5];
    const float* W_z     = (const float*)d_in[6];
    const float* W_r     = (const float*)d_in[7];
    const float* W_h     = (const float*)d_in[8];
    const float* g0_Wlin = (const float*)d_in[9];
    const float* g0_blin = (const float*)d_in[10];
    const float* g0_Wattn= (const float*)d_in[11];
    const float* g0_battn= (const float*)d_in[12];
    const float* g1_Wlin = (const float*)d_in[13];
    const float* g1_blin = (const float*)d_in[14];
    const float* g1_Wattn= (const float*)d_in[15];
    const float* g1_battn= (const float*)d_in[16];
    const float* Wp      = (const float*)d_in[17];
    const float* bp      = (const float*)d_in[18];
    const float* Ws      = (const float*)d_in[19];
    const float* bs      = (const float*)d_in[20];

    const int N  = in_sizes[0] / 128;       // 32000
    const int E  = in_sizes[1] / 2;         // 256000
    const int B  = in_sizes[3] / 128;       // 64
    const int L  = in_sizes[4] / (B * 128); // 50
    const int NN = N / B;                   // 500
    const int nb = N >> 8;                  // 125 bins of 256 nodes

    float* out      = (float*)d_out;
    float* prob_out = out;                               // B*(NN-1)
    float* sisr_out = out + (size_t)B * (NN - 1);        // B*NN
    float* h_out    = sisr_out + (size_t)B * NN;         // B*128

    // workspace layout (~33.4 MB)
    unsigned short* aib = (unsigned short*)d_ws;         // N*128 bf16 (ai)
    unsigned* gbb  = (unsigned*)(aib + (size_t)N * 128); // N*64 packed bf16x2 (g rows)
    unsigned short* pair = (unsigned short*)(gbb + (size_t)N * 64);  // N*128 ushort {fp8 y, fp8 aj}
    unsigned short* wc = pair + (size_t)N * 128;         // 2*384*128 bf16 (row-permuted)
    float* bc   = (float*)(wc + 2 * 384 * 128);          // 2*384 f32
    float* pbuf = bc + 768;                              // N f32
    int* cnt0  = (int*)(pbuf + N);                       // N (graph0), N (graph1) contiguous
    int* cnt1  = cnt0 + N;
    unsigned short* esrc0 = (unsigned short*)(cnt1 + N); // N*CAP ushort (graph0), then graph1
    unsigned short* esrc1 = esrc0 + (size_t)N * CAP;
    unsigned* bins = (unsigned*)(esrc1 + (size_t)N * CAP); // 2*nb*CAPB packed edges
    int* binCnt = (int*)(bins + (size_t)2 * nb * CAPB);    // 2*nb

    // --- zero bin counters (1 KB; per-node cnt is fully written by phase B) ---
    hipMemsetAsync(binCnt, 0, (size_t)2 * nb * sizeof(int), stream);

    // --- prep: phase-A partition + weight-combine + GRU ---
    const int nA = (E + PART_CHUNK - 1) / PART_CHUNK;    // 63 blocks per graph
    prep_kernel<<<2 * nA + 387 + B, 256, 0, stream>>>(
        ei0, ei1, binCnt, bins, E, nA, nb,
        g0_Wlin, g0_Wattn, g0_blin, g0_battn,
        g1_Wlin, g1_Wattn, g1_blin, g1_battn,
        wc, bc,
        state_, input_, W_in, W_z, W_r, W_h, h_out, L);

    const int gemmBlks2 = 2 * (N / 64);     // 1000 (col-half split)

    // --- layer-0 GEMM + phase-B bucket build for BOTH graphs (trailing 2*nb blocks) ---
    gemm384<<<gemmBlks2 + 2 * nb, 256, 0, stream>>>(nullptr, x, (const short*)wc, bc, aib, pair,
                                                    bins, binCnt, cnt0, esrc0, N, nb, gemmBlks2);

    // --- layer-0 aggregate ---
    aggregate_kernel<<<(N + 3) / 4, 256, 0, stream>>>(aib, (const unsigned*)pair, cnt0, esrc0, gbb,
                                                      nullptr, nullptr, nullptr, nullptr, nullptr,
                                                      nullptr, nullptr, N, NN, 0);

    // --- layer-1 GEMM (bf16 g) ---
    gemm384<<<gemmBlks2, 256, 0, stream>>>((const short*)gbb, nullptr, (const short*)(wc + 49152), bc + 384, aib, pair,
                                           nullptr, nullptr, nullptr, nullptr, N, nb, gemmBlks2);

    // --- layer-1 aggregate + fused readout ---
    aggregate_kernel<<<(N + 3) / 4, 256, 0, stream>>>(aib, (const unsigned*)pair, cnt1, esrc1, nullptr,
                                                      h_out, Wp, bp, Ws, bs,
                                                      pbuf, sisr_out, N, NN, 1);

    // --- softmax ---
    softmax_kernel<<<B, 512, 0, stream>>>(pbuf, prob_out, NN);
}